// Round 16
// baseline (203.153 us; speedup 1.0000x reference)
//
#include <hip/hip_runtime.h>
#include <hip/hip_bf16.h>
#include <math.h>

#define N_NODES 50000
#define N_EDGES 800000
#define IN_DIM  128
#define OUT_DIM 64
#define LEAKY   0.01f

#define PROJ_ROWS 64
#define PROJ_NB   ((N_NODES + PROJ_ROWS - 1) / PROJ_ROWS)   // 782
#define EDGE_NB   ((N_EDGES + 255) / 256)                   // 3125

#define SCAN_B   1024
#define SCAN_NB  ((N_NODES + SCAN_B - 1) / SCAN_B)          // 49

// native 2x float vector -- accepted by __builtin_nontemporal_store
typedef float vfloat2 __attribute__((ext_vector_type(2)));

// ---------------------------------------------------------------------------
// degree histogram + coalesced rank write. LDS-FREE standalone kernel ->
// 8 blocks/CU (32 waves) to hide the ~500cyc atomic-with-return latency.
// (R7-R15 fused this with proj; the fused kernel's 32KB static LDS capped
// hist at ~33% occupancy and pinned the dispatch at ~50us. R12 proj was
// never measured standalone -- this round isolates it.)
__global__ __launch_bounds__(256) void hist_kernel(
        const int* __restrict__ dst, int* __restrict__ counts,
        int* __restrict__ rank) {
    int i = blockIdx.x * 256 + threadIdx.x;
    if (i < N_EDGES) rank[i] = atomicAdd(&counts[dst[i]], 1);
}

// ---------------------------------------------------------------------------
// z = feat @ W (stored bf16), az epilogue. Thread owns 4 rows x 4 cols;
// kk-rotation by row-group keeps ds_read_b128 conflict-free (R12: 1.6M -> 0).
__global__ __launch_bounds__(256) void proj_kernel(
        const float* __restrict__ feat, const float* __restrict__ W,
        const float* __restrict__ a,
        __hip_bfloat16* __restrict__ zb,
        float* __restrict__ az_src, float* __restrict__ az_dst) {
    __shared__ float fs[PROJ_ROWS * IN_DIM];                // 32 KB
    int tid = threadIdx.x;
    int row0 = blockIdx.x * PROJ_ROWS;
    int nrows = N_NODES - row0; if (nrows > PROJ_ROWS) nrows = PROJ_ROWS;

    const float4* gsrc = (const float4*)(feat + (size_t)row0 * IN_DIM);
    if (nrows == PROJ_ROWS) {
#pragma unroll
        for (int i = 0; i < 8; ++i) {
            int idx = tid + i * 256;
            ((float4*)fs)[idx] = gsrc[idx];
        }
    } else {
        int lim = nrows * (IN_DIM / 4);
#pragma unroll
        for (int i = 0; i < 8; ++i) {
            int idx = tid + i * 256;
            if (idx < lim) ((float4*)fs)[idx] = gsrc[idx];
        }
    }
    __syncthreads();

    int lane  = tid & 63;
    int wv    = tid >> 6;
    int cg    = lane & 15;         // col group: cols cg*4 .. cg*4+3
    int rg    = lane >> 4;         // row subgroup 0..3
    int rbase = wv * 16 + rg * 4;

    float acc[4][4];
#pragma unroll
    for (int r = 0; r < 4; ++r)
#pragma unroll
        for (int c = 0; c < 4; ++c) acc[r][c] = 0.f;

    const float* fr0 = &fs[rbase * IN_DIM];
    for (int kk = 0; kk < IN_DIM / 4; ++kk) {
        int kr = (kk + rg) & 31;   // bank-conflict-free rotation
        float4 w0 = *(const float4*)&W[(kr * 4 + 0) * OUT_DIM + cg * 4];
        float4 w1 = *(const float4*)&W[(kr * 4 + 1) * OUT_DIM + cg * 4];
        float4 w2 = *(const float4*)&W[(kr * 4 + 2) * OUT_DIM + cg * 4];
        float4 w3 = *(const float4*)&W[(kr * 4 + 3) * OUT_DIM + cg * 4];
#pragma unroll
        for (int r = 0; r < 4; ++r) {
            float4 f = *(const float4*)&fr0[r * IN_DIM + kr * 4];
            acc[r][0] = fmaf(f.x, w0.x, acc[r][0]);
            acc[r][1] = fmaf(f.x, w0.y, acc[r][1]);
            acc[r][2] = fmaf(f.x, w0.z, acc[r][2]);
            acc[r][3] = fmaf(f.x, w0.w, acc[r][3]);
            acc[r][0] = fmaf(f.y, w1.x, acc[r][0]);
            acc[r][1] = fmaf(f.y, w1.y, acc[r][1]);
            acc[r][2] = fmaf(f.y, w1.z, acc[r][2]);
            acc[r][3] = fmaf(f.y, w1.w, acc[r][3]);
            acc[r][0] = fmaf(f.z, w2.x, acc[r][0]);
            acc[r][1] = fmaf(f.z, w2.y, acc[r][1]);
            acc[r][2] = fmaf(f.z, w2.z, acc[r][2]);
            acc[r][3] = fmaf(f.z, w2.w, acc[r][3]);
            acc[r][0] = fmaf(f.w, w3.x, acc[r][0]);
            acc[r][1] = fmaf(f.w, w3.y, acc[r][1]);
            acc[r][2] = fmaf(f.w, w3.z, acc[r][2]);
            acc[r][3] = fmaf(f.w, w3.w, acc[r][3]);
        }
    }

    float4 a1 = *(const float4*)&a[cg * 4];
    float4 a2 = *(const float4*)&a[OUT_DIM + cg * 4];
#pragma unroll
    for (int r = 0; r < 4; ++r) {
        int row = row0 + rbase + r;
        if (row < N_NODES) {
            __hip_bfloat16 z0 = __float2bfloat16(acc[r][0]);
            __hip_bfloat16 z1 = __float2bfloat16(acc[r][1]);
            __hip_bfloat16 z2 = __float2bfloat16(acc[r][2]);
            __hip_bfloat16 z3 = __float2bfloat16(acc[r][3]);
            ushort4 zp;
            zp.x = *(unsigned short*)&z0;
            zp.y = *(unsigned short*)&z1;
            zp.z = *(unsigned short*)&z2;
            zp.w = *(unsigned short*)&z3;
            *(ushort4*)&zb[(size_t)row * OUT_DIM + cg * 4] = zp;

            float s1 = acc[r][0] * a1.x + acc[r][1] * a1.y +
                       acc[r][2] * a1.z + acc[r][3] * a1.w;
            float s2 = acc[r][0] * a2.x + acc[r][1] * a2.y +
                       acc[r][2] * a2.z + acc[r][3] * a2.w;
#pragma unroll
            for (int off = 1; off < 16; off <<= 1) {
                s1 += __shfl_xor(s1, off, 64);
                s2 += __shfl_xor(s2, off, 64);
            }
            if (cg == 0) { az_src[row] = s1; az_dst[row] = s2; }
        }
    }
}

// ---------------------------------------------------------------------------
// scan step 1: per-block exclusive scan, block totals out
__global__ __launch_bounds__(SCAN_B) void scan1_kernel(
        const int* __restrict__ counts, int* __restrict__ offsets,
        int* __restrict__ blocksums) {
    __shared__ int s[SCAN_B];
    int i = blockIdx.x * SCAN_B + threadIdx.x;
    int v = (i < N_NODES) ? counts[i] : 0;
    s[threadIdx.x] = v;
    __syncthreads();
    for (int off = 1; off < SCAN_B; off <<= 1) {
        int t = (threadIdx.x >= off) ? s[threadIdx.x - off] : 0;
        __syncthreads();
        s[threadIdx.x] += t;
        __syncthreads();
    }
    if (i < N_NODES) offsets[i] = s[threadIdx.x] - v;
    if (threadIdx.x == SCAN_B - 1) blocksums[blockIdx.x] = s[SCAN_B - 1];
}

// scan step 2+3 fused: every block wave-scans the 49 block sums itself,
// then adds its block offset; seal offsets[N]
__global__ __launch_bounds__(SCAN_B) void scan3_kernel(
        int* __restrict__ offsets, const int* __restrict__ blocksums) {
    __shared__ int bs[64];
    if (threadIdx.x < 64) {
        int lane = threadIdx.x;
        int v = (lane < SCAN_NB) ? blocksums[lane] : 0;
        int inc = v;
#pragma unroll
        for (int off = 1; off < 64; off <<= 1) {
            int t = __shfl_up(inc, off, 64);
            if (lane >= off) inc += t;
        }
        bs[lane] = inc - v;
    }
    __syncthreads();
    int i = blockIdx.x * SCAN_B + threadIdx.x;
    if (i < N_NODES) offsets[i] += bs[blockIdx.x];
    if (i == 0) offsets[N_NODES] = N_EDGES;
}

// ---------------------------------------------------------------------------
// CSR build, atomic-free: pos = offsets[dst] + rank. Emits an 8B record
// (src, az_src[src]) per edge via NON-TEMPORAL store (no dirty-line amp).
__global__ __launch_bounds__(256) void build_csr_kernel(
        const int* __restrict__ src, const int* __restrict__ dst,
        const int* __restrict__ rank, const int* __restrict__ offsets,
        const float* __restrict__ az_src, vfloat2* __restrict__ edge_rec) {
    int i = blockIdx.x * 256 + threadIdx.x;
    if (i >= N_EDGES) return;
    int t = dst[i];
    int s = src[i];
    int pos = offsets[t] + rank[i];    // offsets L2-hot (200KB)
    vfloat2 rec;
    rec.x = __int_as_float(s);
    rec.y = az_src[s];                 // 200KB L2-hot gather
    __builtin_nontemporal_store(rec, &edge_rec[pos]);
}

// ---------------------------------------------------------------------------
// single-pass softmax-aggregation. One wave per node, lane = dim.
// Per edge: ONE 8B record load + one 128B z-row gather; 4 independent chains.
__global__ __launch_bounds__(256) void node_fused_kernel(
        const int* __restrict__ offsets, const vfloat2* __restrict__ edge_rec,
        const float* __restrict__ az_dst,
        const __hip_bfloat16* __restrict__ zb, float* __restrict__ h) {
    int lane = threadIdx.x & 63;
    int w    = threadIdx.x >> 6;
    int t    = blockIdx.x * 4 + w;
    if (t >= N_NODES) return;
    int beg = offsets[t];
    int end = offsets[t + 1];
    float az_d = az_dst[t];

    float acc0 = 0.f, acc1 = 0.f, acc2 = 0.f, acc3 = 0.f;
    float ss0 = 0.f, ss1 = 0.f, ss2 = 0.f, ss3 = 0.f;
    int i = beg;
    for (; i + 4 <= end; i += 4) {
        vfloat2 r0 = edge_rec[i];
        vfloat2 r1 = edge_rec[i + 1];
        vfloat2 r2 = edge_rec[i + 2];
        vfloat2 r3 = edge_rec[i + 3];
        float v0 = r0.y + az_d;
        float v1 = r1.y + az_d;
        float v2 = r2.y + az_d;
        float v3 = r3.y + az_d;
        v0 = v0 > 0.f ? v0 : LEAKY * v0;
        v1 = v1 > 0.f ? v1 : LEAKY * v1;
        v2 = v2 > 0.f ? v2 : LEAKY * v2;
        v3 = v3 > 0.f ? v3 : LEAKY * v3;
        float x0 = __expf(v0), x1 = __expf(v1);
        float x2 = __expf(v2), x3 = __expf(v3);
        ss0 += x0; ss1 += x1; ss2 += x2; ss3 += x3;
        int s0 = __float_as_int(r0.x);
        int s1 = __float_as_int(r1.x);
        int s2 = __float_as_int(r2.x);
        int s3 = __float_as_int(r3.x);
        acc0 = fmaf(x0, __bfloat162float(zb[(size_t)s0 * OUT_DIM + lane]), acc0);
        acc1 = fmaf(x1, __bfloat162float(zb[(size_t)s1 * OUT_DIM + lane]), acc1);
        acc2 = fmaf(x2, __bfloat162float(zb[(size_t)s2 * OUT_DIM + lane]), acc2);
        acc3 = fmaf(x3, __bfloat162float(zb[(size_t)s3 * OUT_DIM + lane]), acc3);
    }
    for (; i < end; ++i) {
        vfloat2 r0 = edge_rec[i];
        float v0 = r0.y + az_d;
        v0 = v0 > 0.f ? v0 : LEAKY * v0;
        float x0 = __expf(v0);
        ss0 += x0;
        int s0 = __float_as_int(r0.x);
        acc0 = fmaf(x0, __bfloat162float(zb[(size_t)s0 * OUT_DIM + lane]), acc0);
    }
    float ssum = (ss0 + ss1) + (ss2 + ss3);
    float inv  = (end > beg) ? 1.f / ssum : 0.f;
    h[(size_t)t * OUT_DIM + lane] = ((acc0 + acc1) + (acc2 + acc3)) * inv;
}

// ---------------------------------------------------------------------------
extern "C" void kernel_launch(void* const* d_in, const int* in_sizes, int n_in,
                              void* d_out, int out_size, void* d_ws, size_t ws_size,
                              hipStream_t stream) {
    const float* feat = (const float*)d_in[0];
    const int*   src  = (const int*)  d_in[1];
    const int*   dst  = (const int*)  d_in[2];
    const float* W    = (const float*)d_in[3];
    const float* a    = (const float*)d_in[4];
    float* h = (float*)d_out;

    // workspace layout (8B-aligned edge_rec first)
    vfloat2* edge_rec = (vfloat2*)d_ws;                      // E vfloat2
    float*  az_src    = (float*)(edge_rec + N_EDGES);        // N
    float*  az_dst    = az_src + N_NODES;                    // N
    int*    counts    = (int*)(az_dst + N_NODES);            // N
    int*    offsets   = counts + N_NODES;                    // N+1
    int*    blocksums = offsets + N_NODES + 1;               // 64
    int*    rank      = blocksums + 64;                      // E
    __hip_bfloat16* zb = (__hip_bfloat16*)(rank + N_EDGES);  // N*64

    (void)hipMemsetAsync(counts, 0, sizeof(int) * N_NODES, stream);

    hist_kernel<<<EDGE_NB, 256, 0, stream>>>(dst, counts, rank);
    proj_kernel<<<PROJ_NB, 256, 0, stream>>>(feat, W, a, zb, az_src, az_dst);

    scan1_kernel<<<SCAN_NB, SCAN_B, 0, stream>>>(counts, offsets, blocksums);
    scan3_kernel<<<SCAN_NB, SCAN_B, 0, stream>>>(offsets, blocksums);

    build_csr_kernel<<<EDGE_NB, 256, 0, stream>>>(src, dst, rank, offsets,
                                                  az_src, edge_rec);

    node_fused_kernel<<<(N_NODES + 3) / 4, 256, 0, stream>>>(
        offsets, edge_rec, az_dst, zb, h);
}

// Round 17
// 178.337 us; speedup vs baseline: 1.1391x; 1.1391x over previous
//
#include <hip/hip_runtime.h>
#include <hip/hip_bf16.h>
#include <math.h>

#define N_NODES 50000
#define N_EDGES 800000
#define IN_DIM  128
#define OUT_DIM 64
#define LEAKY   0.01f

#define PROJ_ROWS 64
#define PROJ_NB   ((N_NODES + PROJ_ROWS - 1) / PROJ_ROWS)   // 782
#define EDGE_NB   ((N_EDGES + 255) / 256)                   // 3125

#define SCAN_B   1024
#define SCAN_NB  ((N_NODES + SCAN_B - 1) / SCAN_B)          // 49

// native 2x float vector -- accepted by __builtin_nontemporal_store
typedef float vfloat2 __attribute__((ext_vector_type(2)));

// ---------------------------------------------------------------------------
// FUSED: blocks [0, PROJ_NB) do z = feat @ W (+az epilogue);
//        blocks [PROJ_NB, ...) do degree histogram + coalesced rank write.
// Fusion is load-bearing (R16 unfuse: +12us): the 800k atomic-with-return
// ops are coherent-point-bound (~50us) wherever they run; proj rides free.
__global__ __launch_bounds__(256) void proj_hist_kernel(
        const float* __restrict__ feat, const float* __restrict__ W,
        const float* __restrict__ a,
        __hip_bfloat16* __restrict__ zb,
        float* __restrict__ az_src, float* __restrict__ az_dst,
        const int* __restrict__ dst, int* __restrict__ counts,
        int* __restrict__ rank) {
    __shared__ float fs[PROJ_ROWS * IN_DIM];                // 32 KB
    int tid = threadIdx.x;

    if (blockIdx.x >= PROJ_NB) {
        int i = (blockIdx.x - PROJ_NB) * 256 + tid;
        if (i < N_EDGES) rank[i] = atomicAdd(&counts[dst[i]], 1);
        return;
    }

    // ---- projection: thread owns 4 rows x 4 cols; kk-rotation by row-group
    //      keeps ds_read_b128 conflict-free (R12: conflicts 1.6M -> 0)
    int row0 = blockIdx.x * PROJ_ROWS;
    int nrows = N_NODES - row0; if (nrows > PROJ_ROWS) nrows = PROJ_ROWS;

    const float4* gsrc = (const float4*)(feat + (size_t)row0 * IN_DIM);
    if (nrows == PROJ_ROWS) {
#pragma unroll
        for (int i = 0; i < 8; ++i) {
            int idx = tid + i * 256;
            ((float4*)fs)[idx] = gsrc[idx];
        }
    } else {
        int lim = nrows * (IN_DIM / 4);
#pragma unroll
        for (int i = 0; i < 8; ++i) {
            int idx = tid + i * 256;
            if (idx < lim) ((float4*)fs)[idx] = gsrc[idx];
        }
    }
    __syncthreads();

    int lane  = tid & 63;
    int wv    = tid >> 6;
    int cg    = lane & 15;         // col group: cols cg*4 .. cg*4+3
    int rg    = lane >> 4;         // row subgroup 0..3
    int rbase = wv * 16 + rg * 4;

    float acc[4][4];
#pragma unroll
    for (int r = 0; r < 4; ++r)
#pragma unroll
        for (int c = 0; c < 4; ++c) acc[r][c] = 0.f;

    const float* fr0 = &fs[rbase * IN_DIM];
    for (int kk = 0; kk < IN_DIM / 4; ++kk) {
        int kr = (kk + rg) & 31;   // bank-conflict-free rotation
        float4 w0 = *(const float4*)&W[(kr * 4 + 0) * OUT_DIM + cg * 4];
        float4 w1 = *(const float4*)&W[(kr * 4 + 1) * OUT_DIM + cg * 4];
        float4 w2 = *(const float4*)&W[(kr * 4 + 2) * OUT_DIM + cg * 4];
        float4 w3 = *(const float4*)&W[(kr * 4 + 3) * OUT_DIM + cg * 4];
#pragma unroll
        for (int r = 0; r < 4; ++r) {
            float4 f = *(const float4*)&fr0[r * IN_DIM + kr * 4];
            acc[r][0] = fmaf(f.x, w0.x, acc[r][0]);
            acc[r][1] = fmaf(f.x, w0.y, acc[r][1]);
            acc[r][2] = fmaf(f.x, w0.z, acc[r][2]);
            acc[r][3] = fmaf(f.x, w0.w, acc[r][3]);
            acc[r][0] = fmaf(f.y, w1.x, acc[r][0]);
            acc[r][1] = fmaf(f.y, w1.y, acc[r][1]);
            acc[r][2] = fmaf(f.y, w1.z, acc[r][2]);
            acc[r][3] = fmaf(f.y, w1.w, acc[r][3]);
            acc[r][0] = fmaf(f.z, w2.x, acc[r][0]);
            acc[r][1] = fmaf(f.z, w2.y, acc[r][1]);
            acc[r][2] = fmaf(f.z, w2.z, acc[r][2]);
            acc[r][3] = fmaf(f.z, w2.w, acc[r][3]);
            acc[r][0] = fmaf(f.w, w3.x, acc[r][0]);
            acc[r][1] = fmaf(f.w, w3.y, acc[r][1]);
            acc[r][2] = fmaf(f.w, w3.z, acc[r][2]);
            acc[r][3] = fmaf(f.w, w3.w, acc[r][3]);
        }
    }

    float4 a1 = *(const float4*)&a[cg * 4];
    float4 a2 = *(const float4*)&a[OUT_DIM + cg * 4];
#pragma unroll
    for (int r = 0; r < 4; ++r) {
        int row = row0 + rbase + r;
        if (row < N_NODES) {
            __hip_bfloat16 z0 = __float2bfloat16(acc[r][0]);
            __hip_bfloat16 z1 = __float2bfloat16(acc[r][1]);
            __hip_bfloat16 z2 = __float2bfloat16(acc[r][2]);
            __hip_bfloat16 z3 = __float2bfloat16(acc[r][3]);
            ushort4 zp;
            zp.x = *(unsigned short*)&z0;
            zp.y = *(unsigned short*)&z1;
            zp.z = *(unsigned short*)&z2;
            zp.w = *(unsigned short*)&z3;
            *(ushort4*)&zb[(size_t)row * OUT_DIM + cg * 4] = zp;

            float s1 = acc[r][0] * a1.x + acc[r][1] * a1.y +
                       acc[r][2] * a1.z + acc[r][3] * a1.w;
            float s2 = acc[r][0] * a2.x + acc[r][1] * a2.y +
                       acc[r][2] * a2.z + acc[r][3] * a2.w;
#pragma unroll
            for (int off = 1; off < 16; off <<= 1) {
                s1 += __shfl_xor(s1, off, 64);
                s2 += __shfl_xor(s2, off, 64);
            }
            if (cg == 0) { az_src[row] = s1; az_dst[row] = s2; }
        }
    }
}

// ---------------------------------------------------------------------------
// scan step 1: per-block exclusive scan, block totals out
__global__ __launch_bounds__(SCAN_B) void scan1_kernel(
        const int* __restrict__ counts, int* __restrict__ offsets,
        int* __restrict__ blocksums) {
    __shared__ int s[SCAN_B];
    int i = blockIdx.x * SCAN_B + threadIdx.x;
    int v = (i < N_NODES) ? counts[i] : 0;
    s[threadIdx.x] = v;
    __syncthreads();
    for (int off = 1; off < SCAN_B; off <<= 1) {
        int t = (threadIdx.x >= off) ? s[threadIdx.x - off] : 0;
        __syncthreads();
        s[threadIdx.x] += t;
        __syncthreads();
    }
    if (i < N_NODES) offsets[i] = s[threadIdx.x] - v;
    if (threadIdx.x == SCAN_B - 1) blocksums[blockIdx.x] = s[SCAN_B - 1];
}

// scan step 2+3 fused: every block wave-scans the 49 block sums itself,
// then adds its block offset; seal offsets[N]
__global__ __launch_bounds__(SCAN_B) void scan3_kernel(
        int* __restrict__ offsets, const int* __restrict__ blocksums) {
    __shared__ int bs[64];
    if (threadIdx.x < 64) {
        int lane = threadIdx.x;
        int v = (lane < SCAN_NB) ? blocksums[lane] : 0;
        int inc = v;
#pragma unroll
        for (int off = 1; off < 64; off <<= 1) {
            int t = __shfl_up(inc, off, 64);
            if (lane >= off) inc += t;
        }
        bs[lane] = inc - v;
    }
    __syncthreads();
    int i = blockIdx.x * SCAN_B + threadIdx.x;
    if (i < N_NODES) offsets[i] += bs[blockIdx.x];
    if (i == 0) offsets[N_NODES] = N_EDGES;
}

// ---------------------------------------------------------------------------
// CSR build, atomic-free: pos = offsets[dst] + rank. Emits an 8B record
// (src, az_src[src]) per edge via NON-TEMPORAL store (no dirty-line amp).
// Carrying az in the record makes node's load chain 2-deep (rec -> z-row).
__global__ __launch_bounds__(256) void build_csr_kernel(
        const int* __restrict__ src, const int* __restrict__ dst,
        const int* __restrict__ rank, const int* __restrict__ offsets,
        const float* __restrict__ az_src, vfloat2* __restrict__ edge_rec) {
    int i = blockIdx.x * 256 + threadIdx.x;
    if (i >= N_EDGES) return;
    int t = dst[i];
    int s = src[i];
    int pos = offsets[t] + rank[i];    // offsets L2-hot (200KB)
    vfloat2 rec;
    rec.x = __int_as_float(s);
    rec.y = az_src[s];                 // 200KB L2-hot gather
    __builtin_nontemporal_store(rec, &edge_rec[pos]);
}

// ---------------------------------------------------------------------------
// softmax-aggregation, TWO nodes per wave: half-wave (32 lanes) per node,
// each lane owns a packed bf16x2 dim pair. Every memory instruction serves
// 2 edges (one per half) -> per-edge issue halved, MLP doubled vs R12.
// zb viewed as uint (bf16 pair); 4 independent load chains per half.
__global__ __launch_bounds__(256) void node_fused_kernel(
        const int* __restrict__ offsets, const vfloat2* __restrict__ edge_rec,
        const float* __restrict__ az_dst,
        const unsigned int* __restrict__ zbp, float* __restrict__ h) {
    int lane = threadIdx.x & 63;
    int w    = threadIdx.x >> 6;           // wave 0..3
    int half = lane >> 5;                  // 0 or 1
    int sl   = lane & 31;                  // dim-pair index 0..31
    int t    = blockIdx.x * 8 + w * 2 + half;
    if (t >= N_NODES) return;
    int beg = offsets[t];
    int end = offsets[t + 1];
    float az_d = az_dst[t];

    float al0 = 0.f, ah0 = 0.f, al1 = 0.f, ah1 = 0.f;
    float al2 = 0.f, ah2 = 0.f, al3 = 0.f, ah3 = 0.f;
    float sm0 = 0.f, sm1 = 0.f, sm2 = 0.f, sm3 = 0.f;
    int k = beg;
    for (; k + 4 <= end; k += 4) {
        vfloat2 r0 = edge_rec[k];
        vfloat2 r1 = edge_rec[k + 1];
        vfloat2 r2 = edge_rec[k + 2];
        vfloat2 r3 = edge_rec[k + 3];
        float v0 = r0.y + az_d;
        float v1 = r1.y + az_d;
        float v2 = r2.y + az_d;
        float v3 = r3.y + az_d;
        v0 = v0 > 0.f ? v0 : LEAKY * v0;
        v1 = v1 > 0.f ? v1 : LEAKY * v1;
        v2 = v2 > 0.f ? v2 : LEAKY * v2;
        v3 = v3 > 0.f ? v3 : LEAKY * v3;
        float x0 = __expf(v0), x1 = __expf(v1);
        float x2 = __expf(v2), x3 = __expf(v3);
        sm0 += x0; sm1 += x1; sm2 += x2; sm3 += x3;
        unsigned z0 = zbp[(size_t)__float_as_int(r0.x) * 32 + sl];
        unsigned z1 = zbp[(size_t)__float_as_int(r1.x) * 32 + sl];
        unsigned z2 = zbp[(size_t)__float_as_int(r2.x) * 32 + sl];
        unsigned z3 = zbp[(size_t)__float_as_int(r3.x) * 32 + sl];
        al0 = fmaf(x0, __int_as_float(z0 << 16),        al0);
        ah0 = fmaf(x0, __int_as_float(z0 & 0xffff0000u), ah0);
        al1 = fmaf(x1, __int_as_float(z1 << 16),        al1);
        ah1 = fmaf(x1, __int_as_float(z1 & 0xffff0000u), ah1);
        al2 = fmaf(x2, __int_as_float(z2 << 16),        al2);
        ah2 = fmaf(x2, __int_as_float(z2 & 0xffff0000u), ah2);
        al3 = fmaf(x3, __int_as_float(z3 << 16),        al3);
        ah3 = fmaf(x3, __int_as_float(z3 & 0xffff0000u), ah3);
    }
    for (; k < end; ++k) {
        vfloat2 r0 = edge_rec[k];
        float v0 = r0.y + az_d;
        v0 = v0 > 0.f ? v0 : LEAKY * v0;
        float x0 = __expf(v0);
        sm0 += x0;
        unsigned z0 = zbp[(size_t)__float_as_int(r0.x) * 32 + sl];
        al0 = fmaf(x0, __int_as_float(z0 << 16),        al0);
        ah0 = fmaf(x0, __int_as_float(z0 & 0xffff0000u), ah0);
    }
    float ssum = (sm0 + sm1) + (sm2 + sm3);
    float inv  = (end > beg) ? 1.f / ssum : 0.f;
    float2 st;
    st.x = ((al0 + al1) + (al2 + al3)) * inv;
    st.y = ((ah0 + ah1) + (ah2 + ah3)) * inv;
    *(float2*)&h[(size_t)t * OUT_DIM + sl * 2] = st;
}

// ---------------------------------------------------------------------------
extern "C" void kernel_launch(void* const* d_in, const int* in_sizes, int n_in,
                              void* d_out, int out_size, void* d_ws, size_t ws_size,
                              hipStream_t stream) {
    const float* feat = (const float*)d_in[0];
    const int*   src  = (const int*)  d_in[1];
    const int*   dst  = (const int*)  d_in[2];
    const float* W    = (const float*)d_in[3];
    const float* a    = (const float*)d_in[4];
    float* h = (float*)d_out;

    // workspace layout (8B-aligned edge_rec first)
    vfloat2* edge_rec = (vfloat2*)d_ws;                      // E vfloat2
    float*  az_src    = (float*)(edge_rec + N_EDGES);        // N
    float*  az_dst    = az_src + N_NODES;                    // N
    int*    counts    = (int*)(az_dst + N_NODES);            // N
    int*    offsets   = counts + N_NODES;                    // N+1
    int*    blocksums = offsets + N_NODES + 1;               // 64
    int*    rank      = blocksums + 64;                      // E
    __hip_bfloat16* zb = (__hip_bfloat16*)(rank + N_EDGES);  // N*64

    (void)hipMemsetAsync(counts, 0, sizeof(int) * N_NODES, stream);

    proj_hist_kernel<<<PROJ_NB + EDGE_NB, 256, 0, stream>>>(
        feat, W, a, zb, az_src, az_dst, dst, counts, rank);

    scan1_kernel<<<SCAN_NB, SCAN_B, 0, stream>>>(counts, offsets, blocksums);
    scan3_kernel<<<SCAN_NB, SCAN_B, 0, stream>>>(offsets, blocksums);

    build_csr_kernel<<<EDGE_NB, 256, 0, stream>>>(src, dst, rank, offsets,
                                                  az_src, edge_rec);

    node_fused_kernel<<<(N_NODES + 7) / 8, 256, 0, stream>>>(
        offsets, edge_rec, az_dst, (const unsigned int*)zb, h);
}